// Round 1
// baseline (145.145 us; speedup 1.0000x reference)
//
#include <hip/hip_runtime.h>
#include <math.h>

#define B_  64
#define O_  512
#define N_  784
#define M_  1024
#define BIGV 1e10f

// Kernel 1: per-row e = exp(1.79*x), stable ascending sort of 784 values
// (padded to 1024 with +inf), emitting sorted keys s[b][j] and argsort idx[b][j].
// One block per row, 256 threads, bitonic sort on (key, idx) lexicographic
// (idx payload unique -> strict total order == stable sort).
__global__ __launch_bounds__(256) void snn_sort(const float* __restrict__ x,
                                                float* __restrict__ s_out,
                                                int* __restrict__ i_out)
{
    __shared__ float sk[M_];
    __shared__ int   sv[M_];
    const int b   = blockIdx.x;
    const int tid = threadIdx.x;

    for (int i = tid; i < M_; i += 256) {
        sk[i] = (i < N_) ? expf(x[b * N_ + i] * 1.79f) : INFINITY;
        sv[i] = i;
    }
    __syncthreads();

    for (int k = 2; k <= M_; k <<= 1) {
        for (int j = k >> 1; j > 0; j >>= 1) {
            #pragma unroll
            for (int base = 0; base < M_; base += 256) {
                int i = base + tid;
                int p = i ^ j;
                if (p > i) {            // each pair handled exactly once
                    float ki = sk[i], kp = sk[p];
                    int   vi = sv[i], vp = sv[p];
                    bool gt = (ki > kp) || ((ki == kp) && (vi > vp));
                    bool up = ((i & k) == 0);
                    if (gt == up) {     // out of order for this direction
                        sk[i] = kp; sk[p] = ki;
                        sv[i] = vp; sv[p] = vi;
                    }
                }
            }
            __syncthreads();
        }
    }

    for (int i = tid; i < N_; i += 256) {
        s_out[b * N_ + i] = sk[i];
        i_out[b * N_ + i] = sv[i];
    }
}

// Kernel 2: wT[n][o] = w[o][n]  (so the main kernel's gather is coalesced in o).
__global__ __launch_bounds__(256) void snn_transpose(const float* __restrict__ w,
                                                     float* __restrict__ wT)
{
    int t = blockIdx.x * 256 + threadIdx.x;
    if (t >= O_ * N_) return;
    int n = t >> 9;        // t / 512
    int o = t & (O_ - 1);  // t % 512
    wT[t] = w[o * N_ + n]; // coalesced write, strided (L2-cached) read
}

// Kernel 3: per-(b,o) scan. cond[j] = (out_all[j] < inp_shift[j]) && (ws_sum[j] > 1),
// out = out_all at first true j (j in [0, N]), else out_all[0].
__global__ __launch_bounds__(128) void snn_main(const float* __restrict__ wT,
                                                const float* __restrict__ s_in,
                                                const int*  __restrict__ i_in,
                                                float* __restrict__ out)
{
    __shared__ float ls[N_];
    __shared__ int   li[N_];
    const int b = blockIdx.x;
    const int o = blockIdx.y * 128 + threadIdx.x;

    for (int i = threadIdx.x; i < N_; i += 128) {
        ls[i] = s_in[b * N_ + i];
        li[i] = i_in[b * N_ + i];
    }
    __syncthreads();

    float res, wprev, mulprev;
    bool  found;

    // j = 0: ws_sum = w0, wim_sum = mul0, inp_shift = +inf
    {
        float w0   = wT[li[0] * O_ + o];
        float s0   = ls[0];
        float mul0 = s0 * w0;
        float den  = fminf(fmaxf(w0 - 1.0f, 1e-10f), BIGV);
        float oa   = mul0 / den;
        res   = oa;                       // default result (index 0) if no cond hits
        found = (oa < INFINITY) && (w0 > 1.0f);
        wprev = w0; mulprev = mul0;
    }

    // j = 1..N-1: adjacent-pair sums; loads are independent (addresses from LDS),
    // unroll keeps several L2 gathers in flight.
    #pragma unroll 4
    for (int j = 1; j < N_; ++j) {
        float wj   = wT[li[j] * O_ + o];
        float sj   = ls[j];
        float mulj = sj * wj;
        float ws   = wj + wprev;
        float wim  = mulj + mulprev;
        float den  = fminf(fmaxf(ws - 1.0f, 1e-10f), BIGV);
        float oa   = wim / den;
        bool cond  = (oa < ls[j - 1]) && (ws > 1.0f);
        if (cond && !found) { res = oa; found = true; }
        wprev = wj; mulprev = mulj;
    }

    // j = N: out_all = BIG, inp_shift = s[N-1], cond2 = true
    if (!found && (BIGV < ls[N_ - 1])) res = BIGV;

    out[b * O_ + o] = res;
}

extern "C" void kernel_launch(void* const* d_in, const int* in_sizes, int n_in,
                              void* d_out, int out_size, void* d_ws, size_t ws_size,
                              hipStream_t stream)
{
    const float* x = (const float*)d_in[0];   // [B, N]
    const float* w = (const float*)d_in[1];   // [O, N]
    float* out = (float*)d_out;               // [B, O]

    char* ws = (char*)d_ws;
    float* wT = (float*)ws;                                         // N*O floats
    float* s  = (float*)(ws + (size_t)N_ * O_ * sizeof(float));     // B*N floats
    int*   ix = (int*)  (ws + (size_t)N_ * O_ * sizeof(float)
                            + (size_t)B_ * N_ * sizeof(float));     // B*N ints

    hipLaunchKernelGGL(snn_sort, dim3(B_), dim3(256), 0, stream, x, s, ix);

    int tot = O_ * N_;
    hipLaunchKernelGGL(snn_transpose, dim3((tot + 255) / 256), dim3(256), 0, stream, w, wT);

    hipLaunchKernelGGL(snn_main, dim3(B_, O_ / 128), dim3(128), 0, stream, wT, s, ix, out);
}

// Round 2
// 52.456 us; speedup vs baseline: 2.7670x; 2.7670x over previous
//
#include <hip/hip_runtime.h>
#include <math.h>

#define B_   64
#define O_   512
#define N_   784
#define M_   1024
#define NCH  8
#define CHJ  98            // NCH * CHJ == N_
#define BIGV 1e10f

// ---------------------------------------------------------------------------
// Kernel 1: per-row e = exp(1.79*x), stable ascending sort (pad to 1024 with
// +inf). Bitonic on (key, idx) lexicographic => identical to stable argsort.
// 512 threads: one compare-exchange per thread per step (512 pairs / step).
// ---------------------------------------------------------------------------
__global__ __launch_bounds__(512) void snn_sort(const float* __restrict__ x,
                                                float* __restrict__ s_out,
                                                int* __restrict__ i_out)
{
    __shared__ float sk[M_];
    __shared__ int   sv[M_];
    const int b   = blockIdx.x;
    const int tid = threadIdx.x;

    for (int i = tid; i < M_; i += 512) {
        sk[i] = (i < N_) ? expf(x[b * N_ + i] * 1.79f) : INFINITY;
        sv[i] = i;
    }
    __syncthreads();

    for (int k = 2; k <= M_; k <<= 1) {
        for (int j = k >> 1; j > 0; j >>= 1) {
            // pair index tid -> element i, partner p = i|j  (p > i always)
            int i = ((tid & ~(j - 1)) << 1) | (tid & (j - 1));
            int p = i | j;
            float ki = sk[i], kp = sk[p];
            int   vi = sv[i], vp = sv[p];
            bool gt = (ki > kp) || ((ki == kp) && (vi > vp));
            bool up = ((i & k) == 0);
            if (gt == up) {
                sk[i] = kp; sk[p] = ki;
                sv[i] = vp; sv[p] = vi;
            }
            __syncthreads();
        }
    }

    for (int i = tid; i < N_; i += 512) {
        s_out[b * N_ + i] = sk[i];
        i_out[b * N_ + i] = sv[i];
    }
}

// ---------------------------------------------------------------------------
// Kernel 2: wT[n][o] = w[o][n]  (main gather becomes coalesced in o)
// ---------------------------------------------------------------------------
__global__ __launch_bounds__(256) void snn_transpose(const float* __restrict__ w,
                                                     float* __restrict__ wT)
{
    int t = blockIdx.x * 256 + threadIdx.x;
    if (t >= O_ * N_) return;
    int n = t >> 9;        // t / 512
    int o = t & (O_ - 1);  // t % 512
    wT[t] = w[o * N_ + n];
}

// ---------------------------------------------------------------------------
// Kernel 3: partial first-hit scan over a j-chunk of 98.
// cond[j] = (wim/den < shift[j]) && (ws > 1), div-free as wim < shift*den
// (den > 0 always after clip). Store (num, den) of first hit; den==0 => none.
// ---------------------------------------------------------------------------
__global__ __launch_bounds__(256) void snn_part(const float* __restrict__ wT,
                                                const float* __restrict__ s_in,
                                                const int*  __restrict__ i_in,
                                                float* __restrict__ pnum,
                                                float* __restrict__ pden)
{
    __shared__ float lls[CHJ + 1];
    __shared__ int   lli[CHJ + 1];
    const int b  = blockIdx.x;
    const int c  = blockIdx.z;
    const int o  = blockIdx.y * 256 + threadIdx.x;
    const int j0 = c * CHJ;

    // stage global j in [j0-1, j0+CHJ-1] at local k = j - j0 + 1
    for (int k = threadIdx.x; k <= CHJ; k += 256) {
        int gj = j0 - 1 + k;
        if (gj >= 0) {
            lls[k] = s_in[b * N_ + gj];
            lli[k] = i_in[b * N_ + gj];
        }
    }
    __syncthreads();

    float wprev, mulprev;
    float fnum = 0.0f, fden = 0.0f;
    bool  fnd = false;
    int   jstart;

    if (c == 0) {
        // j = 0: ws_sum = w0, inp_shift = +inf  (cond1 true for finite mul0)
        float w0   = wT[lli[1] * O_ + o];
        float s0   = lls[1];
        float mul0 = s0 * w0;
        float den0 = fminf(fmaxf(w0 - 1.0f, 1e-10f), BIGV);
        bool cond = (mul0 < INFINITY) && (w0 > 1.0f);
        if (cond) { fnum = mul0; fden = den0; fnd = true; }
        wprev = w0; mulprev = mul0;
        jstart = 1;
    } else {
        wprev   = wT[lli[0] * O_ + o];
        mulprev = lls[0] * wprev;
        jstart  = j0;
    }

    #pragma unroll 4
    for (int j = jstart; j < j0 + CHJ; ++j) {
        int   k     = j - j0 + 1;
        float wj    = wT[lli[k] * O_ + o];
        float sj    = lls[k];
        float shift = lls[k - 1];          // inp_shift[j] = s[j-1]
        float mulj  = sj * wj;
        float ws    = wj + wprev;
        float wim   = mulj + mulprev;
        float den   = fminf(fmaxf(ws - 1.0f, 1e-10f), BIGV);
        bool cond   = (wim < shift * den) && (ws > 1.0f);
        if (cond && !fnd) { fnum = wim; fden = den; fnd = true; }
        wprev = wj; mulprev = mulj;
    }

    int t = b * O_ + o;
    pnum[c * (B_ * O_) + t] = fnum;
    pden[c * (B_ * O_) + t] = fden;        // 0 iff not found (found den >= 1e-10)
}

// ---------------------------------------------------------------------------
// Kernel 4: combine 8 chunk results per (b,o): first chunk with den>0 wins;
// else j=N tail (BIG if BIG < s[N-1]); else default out_all[0].
// ---------------------------------------------------------------------------
__global__ __launch_bounds__(256) void snn_combine(const float* __restrict__ wT,
                                                   const float* __restrict__ s_in,
                                                   const int*  __restrict__ i_in,
                                                   const float* __restrict__ pnum,
                                                   const float* __restrict__ pden,
                                                   float* __restrict__ out)
{
    int t = blockIdx.x * 256 + threadIdx.x;
    if (t >= B_ * O_) return;
    int b = t >> 9;            // / O_
    int o = t & (O_ - 1);

    float num = 0.0f, den = 0.0f;
    bool fnd = false;
    #pragma unroll
    for (int c = 0; c < NCH; ++c) {
        float pd = pden[c * (B_ * O_) + t];
        if (!fnd && pd > 0.0f) {
            num = pnum[c * (B_ * O_) + t];
            den = pd;
            fnd = true;
        }
    }

    float res;
    if (fnd) {
        res = num / den;
    } else {
        float slast = s_in[b * N_ + N_ - 1];
        if (BIGV < slast) {
            res = BIGV;                         // j = N hit
        } else {
            int   li0  = i_in[b * N_];          // default: out_all[0]
            float w0   = wT[li0 * O_ + o];
            float mul0 = s_in[b * N_] * w0;
            float d0   = fminf(fmaxf(w0 - 1.0f, 1e-10f), BIGV);
            res = mul0 / d0;
        }
    }
    out[t] = res;
}

extern "C" void kernel_launch(void* const* d_in, const int* in_sizes, int n_in,
                              void* d_out, int out_size, void* d_ws, size_t ws_size,
                              hipStream_t stream)
{
    const float* x = (const float*)d_in[0];   // [B, N]
    const float* w = (const float*)d_in[1];   // [O, N]
    float* out = (float*)d_out;               // [B, O]

    char* ws = (char*)d_ws;
    size_t off = 0;
    float* wT   = (float*)(ws + off); off += (size_t)N_ * O_ * sizeof(float);
    float* s    = (float*)(ws + off); off += (size_t)B_ * N_ * sizeof(float);
    int*   ix   = (int*)  (ws + off); off += (size_t)B_ * N_ * sizeof(int);
    float* pnum = (float*)(ws + off); off += (size_t)NCH * B_ * O_ * sizeof(float);
    float* pden = (float*)(ws + off); off += (size_t)NCH * B_ * O_ * sizeof(float);

    hipLaunchKernelGGL(snn_sort, dim3(B_), dim3(512), 0, stream, x, s, ix);

    int tot = O_ * N_;
    hipLaunchKernelGGL(snn_transpose, dim3((tot + 255) / 256), dim3(256), 0, stream, w, wT);

    hipLaunchKernelGGL(snn_part, dim3(B_, O_ / 256, NCH), dim3(256), 0, stream,
                       wT, s, ix, pnum, pden);

    hipLaunchKernelGGL(snn_combine, dim3((B_ * O_ + 255) / 256), dim3(256), 0, stream,
                       wT, s, ix, pnum, pden, out);
}